// Round 2
// baseline (499.167 us; speedup 1.0000x reference)
//
#include <hip/hip_runtime.h>
#include <stdint.h>

#define NBATCH 4
#define TQ 2048
#define TKK 8192
#define DM 1024
#define HDIM 64
#define LLEN 512

typedef __bf16 bf16;
typedef __attribute__((ext_vector_type(4))) float f32x4;
typedef __attribute__((ext_vector_type(8))) __bf16 bf16x8;
typedef __attribute__((ext_vector_type(4))) __bf16 bf16x4;

typedef const __attribute__((address_space(1))) void* gas1_t;
typedef __attribute__((address_space(3))) void* las3_t;

__device__ __forceinline__ void gload_lds16(const void* g, void* l) {
  // generic->AS1 via 64-bit int round-trip; generic LDS ptr low 32 bits == LDS offset
  __builtin_amdgcn_global_load_lds((gas1_t)(uintptr_t)g, (las3_t)(uint32_t)(uintptr_t)l, 16, 0, 0);
}

// ---------------- cast fp32 -> bf16 (vectorized x4) ----------------
__global__ void cast_f32_bf16(const float* __restrict__ src, bf16* __restrict__ dst, int n4) {
  int i = blockIdx.x * blockDim.x + threadIdx.x;
  int stride = gridDim.x * blockDim.x;
  for (; i < n4; i += stride) {
    float4 v = ((const float4*)src)[i];
    bf16x4 o;
    o[0] = (bf16)v.x; o[1] = (bf16)v.y; o[2] = (bf16)v.z; o[3] = (bf16)v.w;
    ((bf16x4*)dst)[i] = o;
  }
}

// ---------------- mask -> per-(b,h,l) float multiplier ----------------
__global__ void build_maskf(const int* __restrict__ sm, float* __restrict__ mf) {
  int i = blockIdx.x * blockDim.x + threadIdx.x;  // 64*512 total
  int bh = i >> 9, l = i & 511;
  int b = bh >> 4, h = bh & 15;
  mf[i] = sm[b * TKK + h + 16 * l] ? 1.0f : 0.0f;
}

// ---------------- GEMM-BT + bias (+scale), m97 structure ----------------
// C[m,n] = (sum_k A[m,k]*B[n,k] + bias[n]) * scale ; lda=ldb=ldc=1024
// 128x128 tile, BK=64, 4 waves (2x2), global_load_lds staging (linear LDS).
template<bool OUT_BF16>
__global__ __launch_bounds__(256) void gemm_bt_bias(
    const bf16* __restrict__ A, const bf16* __restrict__ Bm,
    const float* __restrict__ bias, void* __restrict__ Cout, float scale) {
  __shared__ bf16 As[128 * 64];
  __shared__ bf16 Bs[128 * 64];
  const int t = threadIdx.x;
  const int lane = t & 63, w = t >> 6;
  const int wm = w >> 1, wn = w & 1;
  const int m0 = blockIdx.y * 128, n0 = blockIdx.x * 128;
  const int c = lane & 15, g = lane >> 4;
  f32x4 acc[4][4] = {};
  for (int k0 = 0; k0 < DM; k0 += 64) {
    __syncthreads();  // protect LDS from previous iteration's readers
    #pragma unroll
    for (int i = 0; i < 4; ++i) {  // 1024 chunks of 16B per matrix, 4/thread
      int chunk = i * 256 + t;
      int row = chunk >> 3, blk = chunk & 7;
      gload_lds16(A + (size_t)(m0 + row) * DM + k0 + blk * 8, As + chunk * 8);
      gload_lds16(Bm + (size_t)(n0 + row) * DM + k0 + blk * 8, Bs + chunk * 8);
    }
    __syncthreads();  // compiler drains vmcnt before barrier
    #pragma unroll
    for (int kk = 0; kk < 2; ++kk) {
      bf16x8 af[4], bfr[4];
      #pragma unroll
      for (int f = 0; f < 4; ++f)
        af[f] = *(const bf16x8*)(As + (wm * 64 + f * 16 + c) * 64 + kk * 32 + g * 8);
      #pragma unroll
      for (int f = 0; f < 4; ++f)
        bfr[f] = *(const bf16x8*)(Bs + (wn * 64 + f * 16 + c) * 64 + kk * 32 + g * 8);
      #pragma unroll
      for (int mi = 0; mi < 4; ++mi)
        #pragma unroll
        for (int ni = 0; ni < 4; ++ni)
          acc[mi][ni] = __builtin_amdgcn_mfma_f32_16x16x32_bf16(af[mi], bfr[ni], acc[mi][ni], 0, 0, 0);
    }
  }
  #pragma unroll
  for (int ni = 0; ni < 4; ++ni) {
    int n = n0 + wn * 64 + ni * 16 + c;
    float bv = bias[n];
    #pragma unroll
    for (int mi = 0; mi < 4; ++mi) {
      int m = m0 + wm * 64 + mi * 16 + g * 4;
      #pragma unroll
      for (int j = 0; j < 4; ++j) {
        float vv = (acc[mi][ni][j] + bv) * scale;
        if (OUT_BF16) ((bf16*)Cout)[(size_t)(m + j) * DM + n] = (bf16)vv;
        else          ((float*)Cout)[(size_t)(m + j) * DM + n] = vv;
      }
    }
  }
}

// ---------------- sliced K/V projection ----------------
// Per (b,h): C[l,d] = sum_k X[b, h+16*l, k] * W[h*64+d, k] + bias[h*64+d]
// TRANSPOSE==0: write Out[bh][l][d] (K-hat).  TRANSPOSE==1: write Out[bh][d][l] (V^T).
// A reg-staged fp32->bf16 into XOR-swizzled LDS; 128(M) x 64(N) tile, BK=64.
template<int TRANSPOSE>
__global__ __launch_bounds__(256) void kv_proj(
    const float* __restrict__ X, const bf16* __restrict__ W,
    const float* __restrict__ bias, bf16* __restrict__ Out) {
  __shared__ bf16 As[128 * 64];
  __shared__ bf16 Bs[64 * 64];
  const int t = threadIdx.x, lane = t & 63, w = t >> 6;
  const int wm = w >> 1, wn = w & 1;
  const int bh = blockIdx.y, b = bh >> 4, h = bh & 15;
  const int l0 = blockIdx.x * 128;
  const int c = lane & 15, g = lane >> 4;
  f32x4 acc[4][2] = {};
  for (int k0 = 0; k0 < DM; k0 += 64) {
    __syncthreads();
    #pragma unroll
    for (int i = 0; i < 8; ++i) {  // A: 128x64 fp32 = 2048 float4 chunks
      int chunk = i * 256 + t;
      int row = chunk >> 4, q4 = chunk & 15;
      float4 v = *(const float4*)(X + ((size_t)b * TKK + h + 16 * (l0 + row)) * DM + k0 + q4 * 4);
      bf16x4 o;
      o[0] = (bf16)v.x; o[1] = (bf16)v.y; o[2] = (bf16)v.z; o[3] = (bf16)v.w;
      uint32_t byte = (uint32_t)(row * 128 + q4 * 8) ^ (uint32_t)((row & 7) << 4);
      *(bf16x4*)((char*)As + byte) = o;
    }
    #pragma unroll
    for (int i = 0; i < 2; ++i) {  // B: 64x64 bf16 = 512 16B chunks
      int chunk = i * 256 + t;
      int row = chunk >> 3, blk = chunk & 7;
      uint4 v = *(const uint4*)(W + (size_t)(h * 64 + row) * DM + k0 + blk * 8);
      uint32_t byte = (uint32_t)(row * 128 + blk * 16) ^ (uint32_t)((row & 7) << 4);
      *(uint4*)((char*)Bs + byte) = v;
    }
    __syncthreads();
    #pragma unroll
    for (int kk = 0; kk < 2; ++kk) {
      bf16x8 af[4], bfr[2];
      #pragma unroll
      for (int f = 0; f < 4; ++f) {
        int row = wm * 64 + f * 16 + c;
        uint32_t byte = (uint32_t)(row * 128 + (kk * 32 + g * 8) * 2) ^ (uint32_t)((row & 7) << 4);
        af[f] = *(const bf16x8*)((char*)As + byte);
      }
      #pragma unroll
      for (int f = 0; f < 2; ++f) {
        int row = wn * 32 + f * 16 + c;
        uint32_t byte = (uint32_t)(row * 128 + (kk * 32 + g * 8) * 2) ^ (uint32_t)((row & 7) << 4);
        bfr[f] = *(const bf16x8*)((char*)Bs + byte);
      }
      #pragma unroll
      for (int mi = 0; mi < 4; ++mi)
        #pragma unroll
        for (int ni = 0; ni < 2; ++ni)
          acc[mi][ni] = __builtin_amdgcn_mfma_f32_16x16x32_bf16(af[mi], bfr[ni], acc[mi][ni], 0, 0, 0);
    }
  }
  #pragma unroll
  for (int ni = 0; ni < 2; ++ni) {
    int n = wn * 32 + ni * 16 + c;  // d in [0,64)
    float bv = bias[h * 64 + n];
    #pragma unroll
    for (int mi = 0; mi < 4; ++mi) {
      int m = wm * 64 + mi * 16 + g * 4;  // l_local
      if (TRANSPOSE == 0) {
        #pragma unroll
        for (int j = 0; j < 4; ++j)
          Out[((size_t)bh * LLEN + l0 + m + j) * 64 + n] = (bf16)(acc[mi][ni][j] + bv);
      } else {
        bf16x4 o;
        #pragma unroll
        for (int j = 0; j < 4; ++j) o[j] = (bf16)(acc[mi][ni][j] + bv);
        *(bf16x4*)(Out + ((size_t)bh * 64 + n) * LLEN + l0 + m) = o;
      }
    }
  }
}

// ---------------- flash attention over the strided-gathered KV ----------------
__device__ __forceinline__ void stage_kv(const bf16* __restrict__ KH, const bf16* __restrict__ VT,
                                         bf16* Ks, bf16* Vs, int bh, int lt, int t) {
  #pragma unroll
  for (int i = 0; i < 4; ++i) {  // K tile: 128(l) x 64(d) bf16
    int chunk = i * 256 + t, row = chunk >> 3, blk = chunk & 7;
    uint4 v = *(const uint4*)(KH + ((size_t)bh * LLEN + lt * 128 + row) * 64 + blk * 8);
    uint32_t byte = (uint32_t)(row * 128 + blk * 16) ^ (uint32_t)((row & 7) << 4);
    *(uint4*)((char*)Ks + byte) = v;
  }
  #pragma unroll
  for (int i = 0; i < 4; ++i) {  // V^T tile: 64(d) x 128(l) bf16
    int chunk = i * 256 + t, row = chunk >> 4, blk = chunk & 15;
    uint4 v = *(const uint4*)(VT + ((size_t)bh * 64 + row) * LLEN + lt * 128 + blk * 8);
    uint32_t byte = (uint32_t)(row * 256 + blk * 16) ^ (uint32_t)((row & 7) << 4);
    *(uint4*)((char*)Vs + byte) = v;
  }
}

__global__ __launch_bounds__(256) void attn_kernel(
    const bf16* __restrict__ Qp, const bf16* __restrict__ KH, const bf16* __restrict__ VT,
    const float* __restrict__ maskf, bf16* __restrict__ AO) {
  __shared__ bf16 Qs[128 * 64];
  __shared__ bf16 Ks[128 * 64];
  __shared__ bf16 Vs[64 * 128];
  const int t = threadIdx.x, lane = t & 63, w = t >> 6;
  const int bh = blockIdx.y, b = bh >> 4, h = bh & 15;
  const int q0 = blockIdx.x * 128;
  const int c = lane & 15, g = lane >> 4;

  #pragma unroll
  for (int i = 0; i < 4; ++i) {  // stage Q tile: 128(q) x 64(d), 1/8-scaled upstream
    int chunk = i * 256 + t, row = chunk >> 3, blk = chunk & 7;
    uint4 v = *(const uint4*)(Qp + ((size_t)(b * TQ + q0 + row)) * DM + h * 64 + blk * 8);
    uint32_t byte = (uint32_t)(row * 128 + blk * 16) ^ (uint32_t)((row & 7) << 4);
    *(uint4*)((char*)Qs + byte) = v;
  }
  stage_kv(KH, VT, Ks, Vs, bh, 0, t);
  __syncthreads();

  // hoist Q fragments (B-operand of S^T = mfma(K, Q)): lane holds q = w*32 + nf*16 + c
  bf16x8 bq[2][2];
  #pragma unroll
  for (int nf = 0; nf < 2; ++nf)
    #pragma unroll
    for (int kk = 0; kk < 2; ++kk) {
      int row = w * 32 + nf * 16 + c;
      uint32_t byte = (uint32_t)(row * 128 + (kk * 32 + g * 8) * 2) ^ (uint32_t)((row & 7) << 4);
      bq[nf][kk] = *(const bf16x8*)((char*)Qs + byte);
    }

  float m_run[2] = {-1e30f, -1e30f};
  float l_run[2] = {0.0f, 0.0f};
  f32x4 acc_o[4][2] = {};  // O^T: m=d (4 frags), n=q (2 frags)

  #pragma unroll 1
  for (int lt = 0; lt < 4; ++lt) {
    // S^T tile: C[m=l(128), n=q(32)] — softmax axis becomes lane-local-ish
    f32x4 s[8][2] = {};
    #pragma unroll
    for (int kk = 0; kk < 2; ++kk) {
      bf16x8 ak[8];
      #pragma unroll
      for (int mf = 0; mf < 8; ++mf) {
        int row = mf * 16 + c;
        uint32_t byte = (uint32_t)(row * 128 + (kk * 32 + g * 8) * 2) ^ (uint32_t)((row & 7) << 4);
        ak[mf] = *(const bf16x8*)((char*)Ks + byte);
      }
      #pragma unroll
      for (int mf = 0; mf < 8; ++mf)
        #pragma unroll
        for (int nf = 0; nf < 2; ++nf)
          s[mf][nf] = __builtin_amdgcn_mfma_f32_16x16x32_bf16(ak[mf], bq[nf][kk], s[mf][nf], 0, 0, 0);
    }
    // online softmax: lane holds, for q = w*32+nf*16+c, l-values {16*mf + 4*g + j}
    #pragma unroll
    for (int nf = 0; nf < 2; ++nf) {
      float mnew = m_run[nf];
      #pragma unroll
      for (int mf = 0; mf < 8; ++mf)
        #pragma unroll
        for (int j = 0; j < 4; ++j)
          mnew = fmaxf(mnew, s[mf][nf][j]);
      mnew = fmaxf(mnew, __shfl_xor(mnew, 16));
      mnew = fmaxf(mnew, __shfl_xor(mnew, 32));
      float fs = exp2f((m_run[nf] - mnew) * 1.44269504f);
      m_run[nf] = mnew;
      float rs = 0.0f;
      #pragma unroll
      for (int mf = 0; mf < 8; ++mf) {
        float4 mk = *(const float4*)(maskf + (size_t)bh * LLEN + lt * 128 + mf * 16 + 4 * g);
        #pragma unroll
        for (int j = 0; j < 4; ++j) {
          float p = exp2f((s[mf][nf][j] - mnew) * 1.44269504f) * ((const float*)&mk)[j];
          s[mf][nf][j] = p;
          rs += p;
        }
      }
      rs += __shfl_xor(rs, 16);
      rs += __shfl_xor(rs, 32);
      l_run[nf] = l_run[nf] * fs + rs;
      #pragma unroll
      for (int mf = 0; mf < 4; ++mf) acc_o[mf][nf] *= fs;
    }
    // PV: O^T += V^T * P, with bijective k-slot permutation pi(g,s)=32kk+16(s>>2)+4g+(s&3)
    // applied identically to A (V^T from LDS, two b64 reads) and B (P packed in-register).
    #pragma unroll
    for (int kk = 0; kk < 4; ++kk) {
      bf16x8 pb[2];
      #pragma unroll
      for (int nf = 0; nf < 2; ++nf)
        #pragma unroll
        for (int s8 = 0; s8 < 8; ++s8)
          pb[nf][s8] = (bf16)s[kk * 2 + (s8 >> 2)][nf][s8 & 3];
      #pragma unroll
      for (int mf = 0; mf < 4; ++mf) {
        int d = mf * 16 + c;
        uint32_t base = (uint32_t)(d * 256 + (kk * 32 + g * 4) * 2);
        uint32_t swz = (uint32_t)((d & 7) << 4);
        bf16x4 lo = *(const bf16x4*)((char*)Vs + (base ^ swz));
        bf16x4 hi = *(const bf16x4*)((char*)Vs + ((base + 32) ^ swz));
        bf16x8 av = __builtin_shufflevector(lo, hi, 0, 1, 2, 3, 4, 5, 6, 7);
        #pragma unroll
        for (int nf = 0; nf < 2; ++nf)
          acc_o[mf][nf] = __builtin_amdgcn_mfma_f32_16x16x32_bf16(av, pb[nf], acc_o[mf][nf], 0, 0, 0);
      }
    }
    if (lt < 3) {
      __syncthreads();
      stage_kv(KH, VT, Ks, Vs, bh, lt + 1, t);
      __syncthreads();
    }
  }
  // epilogue: divide by row sum, write AO[b*TQ+q][h*64+d] (packed 4 x bf16 along d)
  #pragma unroll
  for (int nf = 0; nf < 2; ++nf) {
    float inv = 1.0f / l_run[nf];
    int qq = q0 + w * 32 + nf * 16 + c;
    #pragma unroll
    for (int mf = 0; mf < 4; ++mf) {
      bf16x4 o;
      #pragma unroll
      for (int j = 0; j < 4; ++j) o[j] = (bf16)(acc_o[mf][nf][j] * inv);
      *(bf16x4*)(AO + ((size_t)(b * TQ + qq)) * DM + h * 64 + mf * 16 + 4 * g) = o;
    }
  }
}

extern "C" void kernel_launch(void* const* d_in, const int* in_sizes, int n_in,
                              void* d_out, int out_size, void* d_ws, size_t ws_size,
                              hipStream_t stream) {
  const float* q   = (const float*)d_in[0];
  const float* k   = (const float*)d_in[1];
  const float* v   = (const float*)d_in[2];
  const int*  smk  = (const int*)d_in[3];
  const float* w_q = (const float*)d_in[4];
  const float* b_q = (const float*)d_in[5];
  const float* w_k = (const float*)d_in[6];
  const float* b_k = (const float*)d_in[7];
  const float* w_v = (const float*)d_in[8];
  const float* b_v = (const float*)d_in[9];
  const float* w_o = (const float*)d_in[10];
  const float* b_o = (const float*)d_in[11];
  float* out = (float*)d_out;

  // workspace layout (bf16 elements): 4 weights | q_bf16 | Q_proj | K_hat | V^T | attn_out | maskf
  bf16* WS  = (bf16*)d_ws;
  bf16* WQ  = WS;
  bf16* WK  = WQ + (1u << 20);
  bf16* WV  = WK + (1u << 20);
  bf16* WO  = WV + (1u << 20);
  bf16* QB  = WO + (1u << 20);
  bf16* QP  = QB + (8u << 20);
  bf16* KH  = QP + (8u << 20);
  bf16* VTT = KH + (2u << 20);
  bf16* AO  = VTT + (2u << 20);
  float* MF = (float*)(AO + (8u << 20));  // total ~64.1 MB

  cast_f32_bf16<<<512, 256, 0, stream>>>(w_q, WQ, 262144);
  cast_f32_bf16<<<512, 256, 0, stream>>>(w_k, WK, 262144);
  cast_f32_bf16<<<512, 256, 0, stream>>>(w_v, WV, 262144);
  cast_f32_bf16<<<512, 256, 0, stream>>>(w_o, WO, 262144);
  cast_f32_bf16<<<2048, 256, 0, stream>>>(q, QB, 2097152);
  build_maskf<<<128, 256, 0, stream>>>(smk, MF);

  // Q = (q @ w_q^T + b_q) * 0.125  (attention scale folded in; exact in bf16)
  gemm_bt_bias<true><<<dim3(8, 64), 256, 0, stream>>>(QB, WQ, b_q, QP, 0.125f);
  // sliced K/V projections: only the consumed 1/16 of each projection
  kv_proj<0><<<dim3(4, 64), 256, 0, stream>>>(k, WK, b_k, KH);
  kv_proj<1><<<dim3(4, 64), 256, 0, stream>>>(v, WV, b_v, VTT);
  // flash attention per (q-tile, b*h)
  attn_kernel<<<dim3(16, 64), 256, 0, stream>>>(QP, KH, VTT, MF, AO);
  // final projection to fp32 output
  gemm_bt_bias<false><<<dim3(8, 64), 256, 0, stream>>>(AO, WO, b_o, out, 1.0f);
}